// Round 6
// baseline (2592.780 us; speedup 1.0000x reference)
//
#include <hip/hip_runtime.h>
#include <hip/hip_bf16.h>

#define NSEQ 512
#define SEGS 511     // L-1
#define CIN  32

typedef float v4f __attribute__((ext_vector_type(4)));

__device__ __forceinline__ float rl(float v, int lane) {
    return __int_as_float(__builtin_amdgcn_readlane(__float_as_int(v), lane));
}

__device__ __forceinline__ float tanhf_fast(float x) {
    // tanh(x) = sign(x) * (1 - e) / (1 + e),  e = exp(-2|x|)  — no overflow path
    float ax = fabsf(x);
    float e = __expf(-2.0f * ax);
#if __has_builtin(__builtin_amdgcn_rcpf)
    float r = (1.0f - e) * __builtin_amdgcn_rcpf(1.0f + e);
#else
    float r = (1.0f - e) / (1.0f + e);
#endif
    return copysignf(r, x);
}

// Block = ONE sequence x 4 waves (256 thr), grid = 512 blocks -> 2 blocks/CU,
// 8 waves/CU = 2 waves/SIMD. The co-resident wave is from a DIFFERENT block
// (unsynchronized), so it fills the SIMD while this block stalls on its
// barrier / LDS latency — that is the whole point of this round.
// Wave w owns h-columns [32w, 32w+32): lane l computes col 32w+(l&31)
// (lane halves duplicate — no cross-lane combine needed). mm2 is a 4-way
// K-split (wave w covers rows 32w..32w+32), one LDS exchange + one barrier
// per RK stage, parity double-buffered.
// W1 in LDS as w1t4[iq][col][4] (iq=i/4): lane reads 16B ds_read_b128;
// lanes 0..31 read 512B contiguous, lanes 32..63 read the SAME addresses
// (same-address broadcast = conflict-free). W2 slice in registers (32/lane).
__global__ __launch_bounds__(256, 2) void node_kernel(
    const float* __restrict__ cA, const float* __restrict__ cB,
    const float* __restrict__ cC, const float* __restrict__ cD,
    const int*   __restrict__ final_index,
    const float* __restrict__ W_init, const float* __restrict__ b_init,
    const float* __restrict__ W1, const float* __restrict__ b1,
    const float* __restrict__ W2, const float* __restrict__ b2,
    const float* __restrict__ W_out, const float* __restrict__ b_out,
    float* __restrict__ out)
{
    __shared__ float w1t4[24 * 128 * 4];   // 48 KiB: [iq][col][e] = W1[4iq+e][col]
    __shared__ float zz[2][4][64];         // [parity][wave][lane] mm2 partials

    const int tid  = threadIdx.x;
    const int lane = tid & 63;
    const int w    = tid >> 6;          // 0..3
    const int b    = blockIdx.x;
    const int ch   = lane & 31;
    const int col  = 32 * w + ch;       // this lane's h column

    // ---- stage W1 into LDS (one-time) ----
    for (int idx = tid; idx < 96 * 128; idx += 256) {
        const int i = idx >> 7, c = idx & 127;
        w1t4[(((i >> 2) << 7) + c) * 4 + (i & 3)] = W1[idx];
    }

    // ---- W2 slice in registers: w2c[j] = W2[32w+j][lane], j=0..31 ----
    float w2c[32];
#pragma unroll
    for (int j = 0; j < 32; ++j) w2c[j] = W2[(32 * w + j) * 64 + lane];
    const float b1c = b1[col];
    const float b2m = b2[lane];

    const float* a_ptr = cA + (size_t)b * SEGS * CIN;
    const float* bp    = cB + (size_t)b * SEGS * CIN;
    const float* cp    = cC + (size_t)b * SEGS * CIN;
    const float* dp    = cD + (size_t)b * SEGS * CIN;

    // ---- z0 = X(0) @ W_init + b_init  (replicated identically in all waves) ----
    float z = b_init[lane];
    {
        float a0 = a_ptr[ch];
#pragma unroll
        for (int i = 0; i < 32; ++i)
            z = fmaf(rl(a0, i), W_init[i * 64 + lane], z);
    }

    const int fi = final_index[b];      // uniform loop bound: ONE seq per block

    // current-segment coeffs (lanes 0..31 meaningful; per-wave copy)
    float acur = a_ptr[ch], bcur = bp[ch], ccur = cp[ch], dcur = dp[ch];
    float k1 = 0.f, k2 = 0.f, k3 = 0.f, k4 = 0.f;

    __syncthreads();   // W1 staged

#define MM_STAGE(YS, XC, PAR, KOUT) do {                                     \
    float h0 = 0.f, h1 = 0.f;                                                \
    _Pragma("unroll")                                                        \
    for (int iq = 0; iq < 16; ++iq) {                                        \
        v4f wv = *reinterpret_cast<const v4f*>(&w1t4[(iq * 128 + col) * 4]); \
        float u0 = rl((YS), 4 * iq),     u1 = rl((YS), 4 * iq + 1);          \
        float u2 = rl((YS), 4 * iq + 2), u3 = rl((YS), 4 * iq + 3);          \
        h0 = fmaf(u0, wv.x, h0); h1 = fmaf(u1, wv.y, h1);                    \
        h0 = fmaf(u2, wv.z, h0); h1 = fmaf(u3, wv.w, h1);                    \
    }                                                                        \
    _Pragma("unroll")                                                        \
    for (int iq = 16; iq < 24; ++iq) {                                       \
        v4f wv = *reinterpret_cast<const v4f*>(&w1t4[(iq * 128 + col) * 4]); \
        const int ib = 4 * (iq - 16);                                        \
        float u0 = rl((XC), ib),     u1 = rl((XC), ib + 1);                  \
        float u2 = rl((XC), ib + 2), u3 = rl((XC), ib + 3);                  \
        h0 = fmaf(u0, wv.x, h0); h1 = fmaf(u1, wv.y, h1);                    \
        h0 = fmaf(u2, wv.z, h0); h1 = fmaf(u3, wv.w, h1);                    \
    }                                                                        \
    float h = tanhf_fast(h0 + h1 + b1c);  /* lane j<32: col 32w+j */         \
    float zp = 0.f, zq = 0.f;                                                \
    _Pragma("unroll")                                                        \
    for (int j = 0; j < 32; j += 2) {                                        \
        zp = fmaf(rl(h, j),     w2c[j],     zp);                             \
        zq = fmaf(rl(h, j + 1), w2c[j + 1], zq);                             \
    }                                                                        \
    zz[PAR][w][lane] = zp + zq;                                              \
    __syncthreads();                                                         \
    float s01 = zz[PAR][0][lane] + zz[PAR][1][lane];                         \
    float s23 = zz[PAR][2][lane] + zz[PAR][3][lane];                         \
    KOUT = tanhf_fast(s01 + s23 + b2m);                                      \
} while (0)

    for (int t = 0; t < fi; ++t) {
        // spline points of this step from current-segment coeffs
        float x0  = acur;
        float i13 = fmaf(dcur, 1.0f / 9.0f, 0.5f * ccur);
        float x13 = fmaf(fmaf(i13, 1.0f / 3.0f, bcur), 1.0f / 3.0f, acur);
        float i23 = fmaf(dcur, 2.0f / 9.0f, 0.5f * ccur);
        float x23 = fmaf(fmaf(i23, 2.0f / 3.0f, bcur), 2.0f / 3.0f, acur);
        float xbl = acur + (bcur + (0.5f * ccur + dcur * (1.0f / 3.0f)));

        // real prefetch of next segment (first use: stage 3 / next iter top)
        const int tn  = (t + 1 < SEGS) ? (t + 1) : (SEGS - 1);
        const int off = tn * CIN + ch;
        float anx = a_ptr[off];
        float bnx = bp[off];
        float cnx = cp[off];
        float dnx = dp[off];

        MM_STAGE(z, x0, 0, k1);
        float ys1 = fmaf(k1, 1.0f / 3.0f, z);
        MM_STAGE(ys1, x13, 1, k2);
        float ys2 = z + (k2 - k1 * (1.0f / 3.0f));
        MM_STAGE(ys2, x23, 0, k3);
        float xb  = (t < SEGS - 1) ? anx : xbl;
        float ys3 = z + (k1 - k2 + k3);
        MM_STAGE(ys3, xb, 1, k4);

        z += (k1 + 3.0f * (k2 + k3) + k4) * 0.125f;
        acur = anx; bcur = bnx; ccur = cnx; dcur = dnx;
    }

    // ---- out[b] = z_fi @ W_out + b_out ----
    if (w == 0 && lane < 10) {
        float acc = b_out[lane];
#pragma unroll
        for (int m = 0; m < 64; ++m)
            acc = fmaf(rl(z, m), W_out[m * 10 + lane], acc);
        out[b * 10 + lane] = acc;
    }
}

extern "C" void kernel_launch(void* const* d_in, const int* in_sizes, int n_in,
                              void* d_out, int out_size, void* d_ws, size_t ws_size,
                              hipStream_t stream) {
    const float* cA     = (const float*)d_in[1];
    const float* cBc    = (const float*)d_in[2];
    const float* cCc    = (const float*)d_in[3];
    const float* cDc    = (const float*)d_in[4];
    const int*   fidx   = (const int*)d_in[5];
    const float* W_init = (const float*)d_in[6];
    const float* b_init = (const float*)d_in[7];
    const float* W1     = (const float*)d_in[8];
    const float* b1     = (const float*)d_in[9];
    const float* W2     = (const float*)d_in[10];
    const float* b2     = (const float*)d_in[11];
    const float* W_out  = (const float*)d_in[12];
    const float* b_out  = (const float*)d_in[13];

    node_kernel<<<dim3(NSEQ), dim3(256), 0, stream>>>(
        cA, cBc, cCc, cDc, fidx, W_init, b_init, W1, b1, W2, b2, W_out, b_out,
        (float*)d_out);
}

// Round 7
// 2295.294 us; speedup vs baseline: 1.1296x; 1.1296x over previous
//
#include <hip/hip_runtime.h>
#include <hip/hip_bf16.h>

#define NSEQ 512
#define SEGS 511     // L-1
#define CIN  32

__device__ __forceinline__ float rl(float v, int lane) {
    return __int_as_float(__builtin_amdgcn_readlane(__float_as_int(v), lane));
}

__device__ __forceinline__ float tanhf_fast(float x) {
    // tanh(x) = sign(x) * (1 - e) / (1 + e),  e = exp(-2|x|)  — no overflow path
    float ax = fabsf(x);
    float e = __expf(-2.0f * ax);
#if __has_builtin(__builtin_amdgcn_rcpf)
    float r = (1.0f - e) * __builtin_amdgcn_rcpf(1.0f + e);
#else
    float r = (1.0f - e) / (1.0f + e);
#endif
    return copysignf(r, x);
}

// Block = ONE sequence x 4 waves (256 thr), grid = 512 -> 2 blocks/CU,
// 8 waves/CU = 2 waves/SIMD (co-resident wave is from the OTHER block,
// unsynchronized -> fills the SIMD during this block's barrier/stalls).
//
// KEY CHANGE vs r6: W1 columns live in REGISTERS (96 floats/lane), not LDS.
// r6's loss came from 4-wave-duplicated ds_read_b128 of W1 saturating the
// shared LDS pipe (~1150 cyc/seq-stage). Lane-half duplication of VALU work
// is free; LDS duplication was not. Per-stage LDS is now only the tiny mm2
// partial exchange: 1 ds_write_b32 + 4 ds_read_b32, 1 barrier, parity
// double-buffered (write[p]; barrier; read[p]; next write of [p] is 2 stages
// later, fenced by the intervening barrier).
//
// Wave w, lane l: mm1 column col = 32w + (l&31) (halves duplicate);
// mm2 K-rows [32w, 32w+32) -- exactly this wave's own h values -- output
// z-column = lane (all 64 distinct).
__global__ __launch_bounds__(256, 2) void node_kernel(
    const float* __restrict__ cA, const float* __restrict__ cB,
    const float* __restrict__ cC, const float* __restrict__ cD,
    const int*   __restrict__ final_index,
    const float* __restrict__ W_init, const float* __restrict__ b_init,
    const float* __restrict__ W1, const float* __restrict__ b1,
    const float* __restrict__ W2, const float* __restrict__ b2,
    const float* __restrict__ W_out, const float* __restrict__ b_out,
    float* __restrict__ out)
{
    __shared__ float zz[2][4][64];         // [parity][wave][lane] mm2 partials

    const int tid  = threadIdx.x;
    const int lane = tid & 63;
    const int w    = tid >> 6;          // 0..3
    const int b    = blockIdx.x;
    const int ch   = lane & 31;
    const int col  = 32 * w + ch;       // this lane's h column

    // ---- W1 column in registers: w1c[i] = W1[i][col]  (coalesced 128B/half-wave) ----
    float w1c[96];
#pragma unroll
    for (int i = 0; i < 96; ++i) w1c[i] = W1[i * 128 + col];
    // ---- W2 slice: w2c[j] = W2[32w+j][lane] ----
    float w2c[32];
#pragma unroll
    for (int j = 0; j < 32; ++j) w2c[j] = W2[(32 * w + j) * 64 + lane];
    const float b1c = b1[col];
    const float b2m = b2[lane];

    const float* a_ptr = cA + (size_t)b * SEGS * CIN;
    const float* bp    = cB + (size_t)b * SEGS * CIN;
    const float* cp    = cC + (size_t)b * SEGS * CIN;
    const float* dp    = cD + (size_t)b * SEGS * CIN;

    // ---- z0 = X(0) @ W_init + b_init  (replicated identically in all waves) ----
    float z = b_init[lane];
    {
        float a0 = a_ptr[ch];
#pragma unroll
        for (int i = 0; i < 32; ++i)
            z = fmaf(rl(a0, i), W_init[i * 64 + lane], z);
    }

    const int fi = final_index[b];      // ONE seq per block: tight loop bound

    // current-segment coeffs (lanes 0..31 meaningful; per-wave copy)
    float acur = a_ptr[ch], bcur = bp[ch], ccur = cp[ch], dcur = dp[ch];
    float k1 = 0.f, k2 = 0.f, k3 = 0.f, k4 = 0.f;

    __syncthreads();

#define MM_STAGE(YS, XC, PAR, KOUT) do {                                     \
    float h0 = 0.f, h1 = 0.f;                                                \
    _Pragma("unroll")                                                        \
    for (int i = 0; i < 64; i += 2) {                                        \
        float u0 = rl((YS), i), u1 = rl((YS), i + 1);                        \
        h0 = fmaf(u0, w1c[i], h0);                                           \
        h1 = fmaf(u1, w1c[i + 1], h1);                                       \
    }                                                                        \
    _Pragma("unroll")                                                        \
    for (int i = 0; i < 32; i += 2) {                                        \
        float u0 = rl((XC), i), u1 = rl((XC), i + 1);                        \
        h0 = fmaf(u0, w1c[64 + i], h0);                                      \
        h1 = fmaf(u1, w1c[64 + i + 1], h1);                                  \
    }                                                                        \
    float h = tanhf_fast(h0 + h1 + b1c);  /* lane j (&31): col 32w+j */      \
    float zp = 0.f, zq = 0.f;                                                \
    _Pragma("unroll")                                                        \
    for (int j = 0; j < 32; j += 2) {                                        \
        zp = fmaf(rl(h, j),     w2c[j],     zp);                             \
        zq = fmaf(rl(h, j + 1), w2c[j + 1], zq);                             \
    }                                                                        \
    zz[PAR][w][lane] = zp + zq;                                              \
    __syncthreads();                                                         \
    float s01 = zz[PAR][0][lane] + zz[PAR][1][lane];                         \
    float s23 = zz[PAR][2][lane] + zz[PAR][3][lane];                         \
    KOUT = tanhf_fast(s01 + s23 + b2m);                                      \
} while (0)

    for (int t = 0; t < fi; ++t) {
        // spline points of this step from current-segment coeffs
        float x0  = acur;
        float i13 = fmaf(dcur, 1.0f / 9.0f, 0.5f * ccur);
        float x13 = fmaf(fmaf(i13, 1.0f / 3.0f, bcur), 1.0f / 3.0f, acur);
        float i23 = fmaf(dcur, 2.0f / 9.0f, 0.5f * ccur);
        float x23 = fmaf(fmaf(i23, 2.0f / 3.0f, bcur), 2.0f / 3.0f, acur);
        float xbl = acur + (bcur + (0.5f * ccur + dcur * (1.0f / 3.0f)));

        // real prefetch of next segment (first use: stage 3 / next iter top)
        const int tn  = (t + 1 < SEGS) ? (t + 1) : (SEGS - 1);
        const int off = tn * CIN + ch;
        float anx = a_ptr[off];
        float bnx = bp[off];
        float cnx = cp[off];
        float dnx = dp[off];

        MM_STAGE(z, x0, 0, k1);
        float ys1 = fmaf(k1, 1.0f / 3.0f, z);
        MM_STAGE(ys1, x13, 1, k2);
        float ys2 = z + (k2 - k1 * (1.0f / 3.0f));
        MM_STAGE(ys2, x23, 0, k3);
        float xb  = (t < SEGS - 1) ? anx : xbl;
        float ys3 = z + (k1 - k2 + k3);
        MM_STAGE(ys3, xb, 1, k4);

        z += (k1 + 3.0f * (k2 + k3) + k4) * 0.125f;
        acur = anx; bcur = bnx; ccur = cnx; dcur = dnx;
    }

    // ---- out[b] = z_fi @ W_out + b_out ----
    if (w == 0 && lane < 10) {
        float acc = b_out[lane];
#pragma unroll
        for (int m = 0; m < 64; ++m)
            acc = fmaf(rl(z, m), W_out[m * 10 + lane], acc);
        out[b * 10 + lane] = acc;
    }
}

extern "C" void kernel_launch(void* const* d_in, const int* in_sizes, int n_in,
                              void* d_out, int out_size, void* d_ws, size_t ws_size,
                              hipStream_t stream) {
    const float* cA     = (const float*)d_in[1];
    const float* cBc    = (const float*)d_in[2];
    const float* cCc    = (const float*)d_in[3];
    const float* cDc    = (const float*)d_in[4];
    const int*   fidx   = (const int*)d_in[5];
    const float* W_init = (const float*)d_in[6];
    const float* b_init = (const float*)d_in[7];
    const float* W1     = (const float*)d_in[8];
    const float* b1     = (const float*)d_in[9];
    const float* W2     = (const float*)d_in[10];
    const float* b2     = (const float*)d_in[11];
    const float* W_out  = (const float*)d_in[12];
    const float* b_out  = (const float*)d_in[13];

    node_kernel<<<dim3(NSEQ), dim3(256), 0, stream>>>(
        cA, cBc, cCc, cDc, fidx, W_init, b_init, W1, b1, W2, b2, W_out, b_out,
        (float*)d_out);
}

// Round 8
// 1368.447 us; speedup vs baseline: 1.8947x; 1.6773x over previous
//
#include <hip/hip_runtime.h>
#include <hip/hip_bf16.h>

#define NSEQ 512
#define SEGS 511     // L-1
#define CIN  32

__device__ __forceinline__ float rl(float v, int lane) {
    return __int_as_float(__builtin_amdgcn_readlane(__float_as_int(v), lane));
}

__device__ __forceinline__ float tanhf_fast(float x) {
    // tanh(x) = sign(x) * (1 - e) / (1 + e),  e = exp(-2|x|)  — no overflow path
    float ax = fabsf(x);
    float e = __expf(-2.0f * ax);
#if __has_builtin(__builtin_amdgcn_rcpf)
    float r = (1.0f - e) * __builtin_amdgcn_rcpf(1.0f + e);
#else
    float r = (1.0f - e) / (1.0f + e);
#endif
    return copysignf(r, x);
}

// Block = ONE sequence x 2 waves (128 thr), grid = 512 -> 2 blocks/CU,
// 4 waves/CU = 1 wave/SIMD (all the real parallelism this problem has:
// 512 seqs x 2 waves of non-duplicated work).
//
// LESSON r5/r6/r7: every variant that STREAMS W1 per stage is bound by the
// shared per-CU pipe doing the streaming (LDS pipe: ~1152 cyc/stage in r5;
// L1/VMEM in r7). Weights must be register-resident. The compiler refused
// before (VGPR=80) because its scheduler over-targets occupancy and remats
// invariant loads into the loop. amdgpu_waves_per_eu(1,1) sets the pressure
// target to 1 wave/EU (512-VGPR budget): with only ~190 VGPRs asked, there
// is no pressure, so no remat. We truly have only 1 wave/SIMD of work, so
// capping the target at 1 costs nothing.
//
// Wave w, lane l: mm1 column col = 64w + l  (cols 0..127, NO duplication);
// mm2 K-rows [64w, 64w+64) = this wave's own h values; one 512 B LDS
// exchange + one barrier per RK stage (parity double-buffered: write[p],
// barrier, read[p]; next write of [p] is 2 stages later, fenced by the
// intervening barrier).
__attribute__((amdgpu_waves_per_eu(1, 1)))
__global__ __launch_bounds__(128) void node_kernel(
    const float* __restrict__ cA, const float* __restrict__ cB,
    const float* __restrict__ cC, const float* __restrict__ cD,
    const int*   __restrict__ final_index,
    const float* __restrict__ W_init, const float* __restrict__ b_init,
    const float* __restrict__ W1, const float* __restrict__ b1,
    const float* __restrict__ W2, const float* __restrict__ b2,
    const float* __restrict__ W_out, const float* __restrict__ b_out,
    float* __restrict__ out)
{
    __shared__ float zz[2][2][64];         // [parity][wave][lane] mm2 partials

    const int tid  = threadIdx.x;
    const int lane = tid & 63;
    const int w    = tid >> 6;          // 0..1
    const int b    = blockIdx.x;
    const int ch   = lane & 31;
    const int col  = 64 * w + lane;     // this lane's h column (all distinct)

    // ---- W1 column in registers: w1c[i] = W1[i][col] (coalesced 256B/wave) ----
    float w1c[96];
#pragma unroll
    for (int i = 0; i < 96; ++i) w1c[i] = W1[i * 128 + col];
    // ---- W2 slice: w2c[j] = W2[64w+j][lane] ----
    float w2c[64];
#pragma unroll
    for (int j = 0; j < 64; ++j) w2c[j] = W2[(64 * w + j) * 64 + lane];
    float b1c = b1[col];
    float b2m = b2[lane];

    // pin: results opaque -> cannot be rematerialized from memory in the loop
#pragma unroll
    for (int i = 0; i < 96; ++i) asm volatile("" : "+v"(w1c[i]));
#pragma unroll
    for (int j = 0; j < 64; ++j) asm volatile("" : "+v"(w2c[j]));
    asm volatile("" : "+v"(b1c));
    asm volatile("" : "+v"(b2m));

    const float* a_ptr = cA + (size_t)b * SEGS * CIN;
    const float* bp    = cB + (size_t)b * SEGS * CIN;
    const float* cp    = cC + (size_t)b * SEGS * CIN;
    const float* dp    = cD + (size_t)b * SEGS * CIN;

    // ---- z0 = X(0) @ W_init + b_init  (replicated identically in both waves) ----
    float z = b_init[lane];
    {
        float a0 = a_ptr[ch];
#pragma unroll
        for (int i = 0; i < 32; ++i)
            z = fmaf(rl(a0, i), W_init[i * 64 + lane], z);
    }

    const int fi = final_index[b];      // ONE seq per block: tight loop bound

    // current-segment coeffs (lanes 0..31 meaningful; per-wave copy)
    float acur = a_ptr[ch], bcur = bp[ch], ccur = cp[ch], dcur = dp[ch];
    float k1 = 0.f, k2 = 0.f, k3 = 0.f, k4 = 0.f;

    __syncthreads();

#define MM_STAGE(YS, XC, PAR, KOUT) do {                                     \
    float h0 = 0.f, h1 = 0.f;                                                \
    _Pragma("unroll")                                                        \
    for (int i = 0; i < 64; i += 2) {                                        \
        float u0 = rl((YS), i), u1 = rl((YS), i + 1);                        \
        h0 = fmaf(u0, w1c[i], h0);                                           \
        h1 = fmaf(u1, w1c[i + 1], h1);                                       \
    }                                                                        \
    _Pragma("unroll")                                                        \
    for (int i = 0; i < 32; i += 2) {                                        \
        float u0 = rl((XC), i), u1 = rl((XC), i + 1);                        \
        h0 = fmaf(u0, w1c[64 + i], h0);                                      \
        h1 = fmaf(u1, w1c[64 + i + 1], h1);                                  \
    }                                                                        \
    float h = tanhf_fast(h0 + h1 + b1c);  /* this lane's col = 64w+lane */   \
    float zp = 0.f, zq = 0.f;                                                \
    _Pragma("unroll")                                                        \
    for (int j = 0; j < 64; j += 2) {                                        \
        zp = fmaf(rl(h, j),     w2c[j],     zp);                             \
        zq = fmaf(rl(h, j + 1), w2c[j + 1], zq);                             \
    }                                                                        \
    zz[PAR][w][lane] = zp + zq;                                              \
    __syncthreads();                                                         \
    float zo = zz[PAR][w ^ 1][lane];                                         \
    KOUT = tanhf_fast(zp + zq + zo + b2m);                                   \
} while (0)

    for (int t = 0; t < fi; ++t) {
        // spline points of this step from current-segment coeffs
        float x0  = acur;
        float i13 = fmaf(dcur, 1.0f / 9.0f, 0.5f * ccur);
        float x13 = fmaf(fmaf(i13, 1.0f / 3.0f, bcur), 1.0f / 3.0f, acur);
        float i23 = fmaf(dcur, 2.0f / 9.0f, 0.5f * ccur);
        float x23 = fmaf(fmaf(i23, 2.0f / 3.0f, bcur), 2.0f / 3.0f, acur);
        float xbl = acur + (bcur + (0.5f * ccur + dcur * (1.0f / 3.0f)));

        // real prefetch of next segment (first use: stage 3 / next iter top)
        const int tn  = (t + 1 < SEGS) ? (t + 1) : (SEGS - 1);
        const int off = tn * CIN + ch;
        float anx = a_ptr[off];
        float bnx = bp[off];
        float cnx = cp[off];
        float dnx = dp[off];

        MM_STAGE(z, x0, 0, k1);
        float ys1 = fmaf(k1, 1.0f / 3.0f, z);
        MM_STAGE(ys1, x13, 1, k2);
        float ys2 = z + (k2 - k1 * (1.0f / 3.0f));
        MM_STAGE(ys2, x23, 0, k3);
        float xb  = (t < SEGS - 1) ? anx : xbl;
        float ys3 = z + (k1 - k2 + k3);
        MM_STAGE(ys3, xb, 1, k4);

        z += (k1 + 3.0f * (k2 + k3) + k4) * 0.125f;
        acur = anx; bcur = bnx; ccur = cnx; dcur = dnx;
    }

    // ---- out[b] = z_fi @ W_out + b_out ----
    if (w == 0 && lane < 10) {
        float acc = b_out[lane];
#pragma unroll
        for (int m = 0; m < 64; ++m)
            acc = fmaf(rl(z, m), W_out[m * 10 + lane], acc);
        out[b * 10 + lane] = acc;
    }
}

extern "C" void kernel_launch(void* const* d_in, const int* in_sizes, int n_in,
                              void* d_out, int out_size, void* d_ws, size_t ws_size,
                              hipStream_t stream) {
    const float* cA     = (const float*)d_in[1];
    const float* cBc    = (const float*)d_in[2];
    const float* cCc    = (const float*)d_in[3];
    const float* cDc    = (const float*)d_in[4];
    const int*   fidx   = (const int*)d_in[5];
    const float* W_init = (const float*)d_in[6];
    const float* b_init = (const float*)d_in[7];
    const float* W1     = (const float*)d_in[8];
    const float* b1     = (const float*)d_in[9];
    const float* W2     = (const float*)d_in[10];
    const float* b2     = (const float*)d_in[11];
    const float* W_out  = (const float*)d_in[12];
    const float* b_out  = (const float*)d_in[13];

    node_kernel<<<dim3(NSEQ), dim3(128), 0, stream>>>(
        cA, cBc, cCc, cDc, fidx, W_init, b_init, W1, b1, W2, b2, W_out, b_out,
        (float*)d_out);
}